// Round 1
// baseline (737.364 us; speedup 1.0000x reference)
//
#include <hip/hip_runtime.h>

// Problem constants (from reference)
#define E_TOT   50000
#define DD      256
#define KSEQ    8
#define NHEAD   4
#define HDIM    64
#define TE      4        // edges per workgroup in fused kernel
#define SCALE_V 0.125f   // HD^-0.5

typedef __attribute__((ext_vector_type(4))) float f32x4;
typedef __attribute__((ext_vector_type(8))) short short8;

__device__ __forceinline__ unsigned short f2bf(float f) {
    unsigned u = __float_as_uint(f);
    u += 0x7fffu + ((u >> 16) & 1u);   // RNE
    return (unsigned short)(u >> 16);
}
__device__ __forceinline__ float bf2f(unsigned short h) {
    return __uint_as_float(((unsigned)h) << 16);
}
__device__ __forceinline__ float gelu_exact(float x) {
    return 0.5f * x * (1.0f + erff(x * 0.70710678118654752440f));
}
__device__ __forceinline__ float sigmoidf(float x) {
    return 1.0f / (1.0f + __expf(-x));
}

// ---------------------------------------------------------------------------
// Kernel P: convert Wq/Wk (f32 [k][n] row-major) -> bf16 transposed [n][k]
// so MFMA B-fragments (8 consecutive k at fixed n) are contiguous 16B loads.
// ---------------------------------------------------------------------------
__global__ void prep_weights(const float* __restrict__ Wq,
                             const float* __restrict__ Wk,
                             unsigned short* __restrict__ wqT,
                             unsigned short* __restrict__ wkT) {
    int i = blockIdx.x * 256 + threadIdx.x;      // grid 512*256 = 131072
    int which = i >> 16;
    int j = i & 65535;                            // flat [k][n]
    int k = j >> 8, n = j & 255;
    const float* W = which ? Wk : Wq;
    unsigned short* o = which ? wkT : wqT;
    o[n * 256 + k] = f2bf(W[j]);
}

// ---------------------------------------------------------------------------
// Kernel A: per-edge cosine similarity + edge-plausibility MLP (fp32).
// One wave (64 lanes) per edge; 4 edges per 256-thread block. E = 12500*4.
// ---------------------------------------------------------------------------
__global__ void score_attr_edge(const float* __restrict__ x_i,
                                const float* __restrict__ x_j,
                                const float* __restrict__ emb,
                                const float* __restrict__ We1,
                                const float* __restrict__ be1,
                                const float* __restrict__ We2,
                                const float* __restrict__ be2,
                                float* __restrict__ attr_out,
                                float* __restrict__ edge_out) {
    __shared__ float sEmb[4][DD];
    const int wv = threadIdx.x >> 6;
    const int l  = threadIdx.x & 63;
    const int e  = blockIdx.x * 4 + wv;

    // ---- (A) cosine similarity ----
    f32x4 a = *(const f32x4*)(x_i + (size_t)e * DD + l * 4);
    f32x4 b = *(const f32x4*)(x_j + (size_t)e * DD + l * 4);
    float dot = a[0]*b[0] + a[1]*b[1] + a[2]*b[2] + a[3]*b[3];
    float ni  = a[0]*a[0] + a[1]*a[1] + a[2]*a[2] + a[3]*a[3];
    float nj  = b[0]*b[0] + b[1]*b[1] + b[2]*b[2] + b[3]*b[3];
    #pragma unroll
    for (int off = 1; off < 64; off <<= 1) {
        dot += __shfl_xor(dot, off);
        ni  += __shfl_xor(ni,  off);
        nj  += __shfl_xor(nj,  off);
    }
    float na = fmaxf(sqrtf(ni), 1e-8f);
    float nb = fmaxf(sqrtf(nj), 1e-8f);
    if (l == 0) attr_out[e] = (dot / (na * nb) + 1.0f) * 0.5f;

    // ---- (C) edge MLP: 256 -> 128 (gelu) -> 1 (sigmoid) ----
    f32x4 ev = *(const f32x4*)(emb + (size_t)e * DD + l * 4);
    sEmb[wv][l*4+0] = ev[0]; sEmb[wv][l*4+1] = ev[1];
    sEmb[wv][l*4+2] = ev[2]; sEmb[wv][l*4+3] = ev[3];
    __syncthreads();

    float acc0 = 0.f, acc1 = 0.f;   // lane l owns hidden cols l and l+64
    #pragma unroll 4
    for (int k = 0; k < DD; ++k) {
        float ek = sEmb[wv][k];
        acc0 = fmaf(ek, We1[k * 128 + l],      acc0);
        acc1 = fmaf(ek, We1[k * 128 + 64 + l], acc1);
    }
    float h0 = gelu_exact(acc0 + be1[l]);
    float h1 = gelu_exact(acc1 + be1[64 + l]);
    float s  = h0 * We2[l] + h1 * We2[64 + l];
    #pragma unroll
    for (int off = 1; off < 64; off <<= 1) s += __shfl_xor(s, off);
    if (l == 0) edge_out[e] = sigmoidf(s + be2[0]);
}

// ---------------------------------------------------------------------------
// Kernel B: fused attention activity score + final combine MLP.
// 4 edges/WG, 256 threads (4 waves). Q/K projections via bf16 MFMA.
// ---------------------------------------------------------------------------
template<int G>
__device__ __forceinline__ void do_gemm(const unsigned short (*A)[DD + 8],
                                        const unsigned short* __restrict__ Wt,
                                        f32x4 acc[2][4], int l, int w) {
    const int lr = l & 15, lq = l >> 4;
    #pragma unroll
    for (int ks = 0; ks < 8; ++ks) {
        const short8 a0 = *(const short8*)&A[lr][ks * 32 + lq * 8];
        const short8 a1 = *(const short8*)&A[16 + lr][ks * 32 + lq * 8];
        #pragma unroll
        for (int n = 0; n < 4; ++n) {
            const int col = (w * 4 + n) * 16 + lr;
            const short8 bv = *(const short8*)(Wt + col * 256 + ks * 32 + lq * 8);
            acc[0][n] = __builtin_amdgcn_mfma_f32_16x16x32_bf16(a0, bv, acc[0][n], 0, 0, 0);
            acc[1][n] = __builtin_amdgcn_mfma_f32_16x16x32_bf16(a1, bv, acc[1][n], 0, 0, 0);
        }
    }
}

__global__ void fused_attn(const float* __restrict__ h_i,
                           const float* __restrict__ h_j,
                           const unsigned short* __restrict__ wqT,
                           const unsigned short* __restrict__ wkT,
                           const float* __restrict__ bq,
                           const float* __restrict__ bk,
                           const float* __restrict__ Wo1,
                           const float* __restrict__ bo1,
                           const float* __restrict__ Wo2,
                           const float* __restrict__ bo2,
                           const float* __restrict__ attr_ws,
                           const float* __restrict__ edge_ws,
                           float* __restrict__ out) {
    // Abf[0]=h_i tile then Q (bf16), Abf[1]=h_j tile then K. +8 pad kills the
    // 512B-stride bank conflict on 16-lane fragment reads.
    __shared__ unsigned short Abf[2][TE * KSEQ][DD + 8];
    __shared__ float actLds[TE];

    const int t = threadIdx.x;
    const int w = t >> 6;          // wave 0..3
    const int l = t & 63;

    // ---- phase 1: load 2*4 edges * 8*256 f32, convert to bf16 in LDS ----
    #pragma unroll
    for (int i = 0; i < 16; ++i) {
        int f  = i * 256 + t;             // float4 index 0..4095
        int T  = f >> 11;                 // 0: h_i, 1: h_j
        int ff = f & 2047;                // float4 within tensor
        const float* src = T ? h_j : h_i;
        f32x4 v = *(const f32x4*)(src + (size_t)blockIdx.x * (TE * KSEQ * DD) + (size_t)ff * 4);
        unsigned short u0 = f2bf(v[0]), u1 = f2bf(v[1]), u2 = f2bf(v[2]), u3 = f2bf(v[3]);
        ushort4 u = make_ushort4(u0, u1, u2, u3);
        *(ushort4*)&Abf[T][ff >> 6][(ff & 63) * 4] = u;
    }
    __syncthreads();

    // ---- phase 2: Q = h_i @ Wq + bq ; K = h_j @ Wk + bk (bf16 MFMA) ----
    f32x4 accQ[2][4] = {};
    f32x4 accK[2][4] = {};
    do_gemm<0>(Abf[0], wqT, accQ, l, w);
    do_gemm<1>(Abf[1], wkT, accK, l, w);
    __syncthreads();   // everyone done READING Abf

    {
        const int lr = l & 15, lq = l >> 4;
        #pragma unroll
        for (int n = 0; n < 4; ++n) {
            const int col = (w * 4 + n) * 16 + lr;
            const float bsq = bq[col], bsk = bk[col];
            #pragma unroll
            for (int m = 0; m < 2; ++m) {
                #pragma unroll
                for (int v = 0; v < 4; ++v) {
                    const int row = m * 16 + lq * 4 + v;  // verified C/D layout
                    Abf[0][row][col] = f2bf(accQ[m][n][v] + bsq);
                    Abf[1][row][col] = f2bf(accK[m][n][v] + bsk);
                }
            }
        }
    }
    __syncthreads();

    // ---- phase 3: scores, softmax diagonal, activity mean ----
    if (t < 128) {
        const int e = t >> 5, h = (t >> 3) & 3, q = t & 7;
        float qv[64];
        #pragma unroll
        for (int c = 0; c < 8; ++c) {
            short8 v = *(const short8*)&Abf[0][e * 8 + q][h * 64 + c * 8];
            #pragma unroll
            for (int j = 0; j < 8; ++j) qv[c * 8 + j] = bf2f((unsigned short)v[j]);
        }
        float sc[8];
        #pragma unroll
        for (int k = 0; k < 8; ++k) {
            float d = 0.f;
            #pragma unroll
            for (int c = 0; c < 8; ++c) {
                short8 kv = *(const short8*)&Abf[1][e * 8 + k][h * 64 + c * 8];
                #pragma unroll
                for (int j = 0; j < 8; ++j) d = fmaf(qv[c * 8 + j], bf2f((unsigned short)kv[j]), d);
            }
            sc[k] = d * SCALE_V;
        }
        float mx = sc[0];
        #pragma unroll
        for (int k = 1; k < 8; ++k) mx = fmaxf(mx, sc[k]);
        float sum = 0.f, pd = 0.f;
        #pragma unroll
        for (int k = 0; k < 8; ++k) {
            float p = __expf(sc[k] - mx);
            sum += p;
            if (k == q) pd = p;
        }
        float dg = pd / sum;                 // softmax diagonal element
        #pragma unroll
        for (int off = 1; off < 32; off <<= 1) dg += __shfl_xor(dg, off);
        if ((t & 31) == 0) actLds[e] = dg * (1.0f / 32.0f);   // mean over NH*K
    }
    __syncthreads();

    // ---- phase 4: final 3 -> 16 -> 1 MLP ----
    if (t < TE) {
        const int ge = blockIdx.x * TE + t;
        const float s0 = attr_ws[ge];
        const float s1 = actLds[t];
        const float s2 = edge_ws[ge];
        float acc = bo2[0];
        #pragma unroll
        for (int j = 0; j < 16; ++j) {
            float z = s0 * Wo1[j] + s1 * Wo1[16 + j] + s2 * Wo1[32 + j] + bo1[j];
            acc += gelu_exact(z) * Wo2[j];
        }
        out[ge] = sigmoidf(acc);
    }
}

// ---------------------------------------------------------------------------
extern "C" void kernel_launch(void* const* d_in, const int* in_sizes, int n_in,
                              void* d_out, int out_size, void* d_ws, size_t ws_size,
                              hipStream_t stream) {
    const float* x_i  = (const float*)d_in[0];
    const float* x_j  = (const float*)d_in[1];
    const float* h_i  = (const float*)d_in[2];
    const float* h_j  = (const float*)d_in[3];
    const float* emb  = (const float*)d_in[4];
    const float* Wq   = (const float*)d_in[5];
    const float* bq   = (const float*)d_in[6];
    const float* Wk   = (const float*)d_in[7];
    const float* bk   = (const float*)d_in[8];
    const float* We1  = (const float*)d_in[9];
    const float* be1  = (const float*)d_in[10];
    const float* We2  = (const float*)d_in[11];
    const float* be2  = (const float*)d_in[12];
    const float* Wo1  = (const float*)d_in[13];
    const float* bo1  = (const float*)d_in[14];
    const float* Wo2  = (const float*)d_in[15];
    const float* bo2  = (const float*)d_in[16];
    float* out = (float*)d_out;

    // workspace layout
    unsigned short* wqT = (unsigned short*)d_ws;              // 131072 B
    unsigned short* wkT = wqT + 65536;                        // 131072 B
    float* attr_ws = (float*)((char*)d_ws + 262144);          // 200000 B
    float* edge_ws = attr_ws + E_TOT;                         // 200000 B

    prep_weights<<<512, 256, 0, stream>>>(Wq, Wk, wqT, wkT);
    score_attr_edge<<<E_TOT / 4, 256, 0, stream>>>(x_i, x_j, emb, We1, be1, We2, be2,
                                                   attr_ws, edge_ws);
    fused_attn<<<E_TOT / TE, 256, 0, stream>>>(h_i, h_j, wqT, wkT, bq, bk,
                                               Wo1, bo1, Wo2, bo2,
                                               attr_ws, edge_ws, out);
}

// Round 2
// 569.799 us; speedup vs baseline: 1.2941x; 1.2941x over previous
//
#include <hip/hip_runtime.h>

// Problem constants (from reference)
#define E_TOT   50000
#define DD      256
#define KSEQ    8
#define NHEAD   4
#define HDIM    64
#define TE      4        // edges per workgroup in fused kernel
#define SCALE_V 0.125f   // HD^-0.5

typedef __attribute__((ext_vector_type(4))) float f32x4;
typedef __attribute__((ext_vector_type(8))) short short8;

__device__ __forceinline__ unsigned short f2bf(float f) {
    unsigned u = __float_as_uint(f);
    u += 0x7fffu + ((u >> 16) & 1u);   // RNE
    return (unsigned short)(u >> 16);
}
__device__ __forceinline__ float bf2f(unsigned short h) {
    return __uint_as_float(((unsigned)h) << 16);
}
__device__ __forceinline__ float gelu_exact(float x) {
    return 0.5f * x * (1.0f + erff(x * 0.70710678118654752440f));
}
__device__ __forceinline__ float sigmoidf(float x) {
    return 1.0f / (1.0f + __expf(-x));
}

// ---------------------------------------------------------------------------
// Kernel P: convert Wq/Wk (f32 [k][n]) -> bf16 transposed [n][k]; also
// convert We1 (f32 [256][128]) -> bf16 same layout.
// ---------------------------------------------------------------------------
__global__ void prep_weights(const float* __restrict__ Wq,
                             const float* __restrict__ Wk,
                             const float* __restrict__ We1,
                             unsigned short* __restrict__ wqT,
                             unsigned short* __restrict__ wkT,
                             unsigned short* __restrict__ wb1) {
    int i = blockIdx.x * 256 + threadIdx.x;      // grid 640*256 = 163840
    if (i < 131072) {
        int which = i >> 16;
        int j = i & 65535;                        // flat [k][n]
        int k = j >> 8, n = j & 255;
        const float* W = which ? Wk : Wq;
        unsigned short* o = which ? wkT : wqT;
        o[n * 256 + k] = f2bf(W[j]);
    } else {
        int j = i - 131072;                       // 0..32767
        wb1[j] = f2bf(We1[j]);
    }
}

// ---------------------------------------------------------------------------
// Kernel A: per-edge cosine similarity + edge-plausibility MLP.
// One wave (64 lanes) per edge; 4 edges per 256-thread block.
// ---------------------------------------------------------------------------
__global__ void score_attr_edge(const float* __restrict__ x_i,
                                const float* __restrict__ x_j,
                                const float* __restrict__ emb,
                                const unsigned short* __restrict__ wb1,
                                const float* __restrict__ be1,
                                const float* __restrict__ We2,
                                const float* __restrict__ be2,
                                float* __restrict__ attr_out,
                                float* __restrict__ edge_out) {
    __shared__ float sEmb[4][DD];
    const int wv = threadIdx.x >> 6;
    const int l  = threadIdx.x & 63;
    const int e  = blockIdx.x * 4 + wv;

    // ---- (A) cosine similarity ----
    f32x4 a = *(const f32x4*)(x_i + (size_t)e * DD + l * 4);
    f32x4 b = *(const f32x4*)(x_j + (size_t)e * DD + l * 4);
    f32x4 ev = *(const f32x4*)(emb + (size_t)e * DD + l * 4);
    float dot = a[0]*b[0] + a[1]*b[1] + a[2]*b[2] + a[3]*b[3];
    float ni  = a[0]*a[0] + a[1]*a[1] + a[2]*a[2] + a[3]*a[3];
    float nj  = b[0]*b[0] + b[1]*b[1] + b[2]*b[2] + b[3]*b[3];
    #pragma unroll
    for (int off = 1; off < 64; off <<= 1) {
        dot += __shfl_xor(dot, off);
        ni  += __shfl_xor(ni,  off);
        nj  += __shfl_xor(nj,  off);
    }
    float na = fmaxf(sqrtf(ni), 1e-8f);
    float nb = fmaxf(sqrtf(nj), 1e-8f);
    if (l == 0) attr_out[e] = (dot / (na * nb) + 1.0f) * 0.5f;

    // ---- (C) edge MLP: 256 -> 128 (gelu) -> 1 (sigmoid); lane l owns
    // hidden cols 2l, 2l+1 (one u32 bf16-pair load per k) ----
    sEmb[wv][l*4+0] = ev[0]; sEmb[wv][l*4+1] = ev[1];
    sEmb[wv][l*4+2] = ev[2]; sEmb[wv][l*4+3] = ev[3];
    __syncthreads();

    float acc0 = 0.f, acc1 = 0.f;
    #pragma unroll 8
    for (int k = 0; k < DD; ++k) {
        float ek = sEmb[wv][k];
        unsigned u = *(const unsigned*)(wb1 + k * 128 + 2 * l);
        acc0 = fmaf(ek, bf2f((unsigned short)(u & 0xffffu)), acc0);
        acc1 = fmaf(ek, bf2f((unsigned short)(u >> 16)),     acc1);
    }
    float h0 = gelu_exact(acc0 + be1[2 * l]);
    float h1 = gelu_exact(acc1 + be1[2 * l + 1]);
    float s  = h0 * We2[2 * l] + h1 * We2[2 * l + 1];
    #pragma unroll
    for (int off = 1; off < 64; off <<= 1) s += __shfl_xor(s, off);
    if (l == 0) edge_out[e] = sigmoidf(s + be2[0]);
}

// ---------------------------------------------------------------------------
// Kernel B: fused attention activity score + final combine MLP.
// 4 edges/WG, 256 threads (4 waves). Q/K projections via bf16 MFMA.
// ---------------------------------------------------------------------------
__device__ __forceinline__ void do_gemm(const unsigned short (*A)[DD + 8],
                                        const unsigned short* __restrict__ Wt,
                                        f32x4 acc[2][4], int l, int w) {
    const int lr = l & 15, lq = l >> 4;
    #pragma unroll
    for (int ks = 0; ks < 8; ++ks) {
        const short8 a0 = *(const short8*)&A[lr][ks * 32 + lq * 8];
        const short8 a1 = *(const short8*)&A[16 + lr][ks * 32 + lq * 8];
        #pragma unroll
        for (int n = 0; n < 4; ++n) {
            const int col = (w * 4 + n) * 16 + lr;
            const short8 bv = *(const short8*)(Wt + col * 256 + ks * 32 + lq * 8);
            acc[0][n] = __builtin_amdgcn_mfma_f32_16x16x32_bf16(a0, bv, acc[0][n], 0, 0, 0);
            acc[1][n] = __builtin_amdgcn_mfma_f32_16x16x32_bf16(a1, bv, acc[1][n], 0, 0, 0);
        }
    }
}

__device__ __forceinline__ void writeback(unsigned short (*A)[DD + 8],
                                          const f32x4 acc[2][4],
                                          const float* __restrict__ bias,
                                          int l, int w) {
    const int lr = l & 15, lq = l >> 4;
    #pragma unroll
    for (int n = 0; n < 4; ++n) {
        const int col = (w * 4 + n) * 16 + lr;
        const float bs = bias[col];
        #pragma unroll
        for (int m = 0; m < 2; ++m) {
            #pragma unroll
            for (int v = 0; v < 4; ++v) {
                const int row = m * 16 + lq * 4 + v;  // verified C/D layout
                A[row][col] = f2bf(acc[m][n][v] + bs);
            }
        }
    }
}

__global__ __launch_bounds__(256, 4)
void fused_attn(const float* __restrict__ h_i,
                const float* __restrict__ h_j,
                const unsigned short* __restrict__ wqT,
                const unsigned short* __restrict__ wkT,
                const float* __restrict__ bq,
                const float* __restrict__ bk,
                const float* __restrict__ Wo1,
                const float* __restrict__ bo1,
                const float* __restrict__ Wo2,
                const float* __restrict__ bo2,
                const float* __restrict__ attr_ws,
                const float* __restrict__ edge_ws,
                float* __restrict__ out) {
    // Abf[0]=h_i tile then Q (bf16), Abf[1]=h_j tile then K. +8 pad kills the
    // 512B-stride bank conflict on 16-lane fragment reads.
    __shared__ unsigned short Abf[2][TE * KSEQ][DD + 8];
    __shared__ float actLds[TE];

    const int t = threadIdx.x;
    const int w = t >> 6;          // wave 0..3
    const int l = t & 63;
    const size_t base = (size_t)blockIdx.x * (TE * KSEQ * DD);

    // ---- phase 1: 16-deep register-staged load of 64 KB f32 (h_i|h_j),
    // then convert to bf16 in LDS. Two unrolled loops so all 16 global
    // loads are in flight before the first vmcnt wait. ----
    f32x4 stg[16];
    #pragma unroll
    for (int i = 0; i < 16; ++i) {
        const int f  = i * 256 + t;           // float4 index 0..4095
        const float* src = (f >> 11) ? h_j : h_i;   // compile-time per i
        stg[i] = *(const f32x4*)(src + base + (size_t)(f & 2047) * 4);
    }
    #pragma unroll
    for (int i = 0; i < 16; ++i) {
        const int f  = i * 256 + t;
        const int T  = f >> 11;
        const int ff = f & 2047;
        ushort4 u = make_ushort4(f2bf(stg[i][0]), f2bf(stg[i][1]),
                                 f2bf(stg[i][2]), f2bf(stg[i][3]));
        *(ushort4*)&Abf[T][ff >> 6][(ff & 63) * 4] = u;
    }
    __syncthreads();

    // ---- phase 2a: Q = h_i @ Wq + bq (reads Abf[0], writes Abf[0]) ----
    {
        f32x4 acc[2][4] = {};
        do_gemm(Abf[0], wqT, acc, l, w);
        __syncthreads();                 // all waves done reading Abf[0]
        writeback(Abf[0], acc, bq, l, w);
    }
    // ---- phase 2b: K = h_j @ Wk + bk (reads Abf[1], writes Abf[1]) ----
    {
        f32x4 acc[2][4] = {};
        do_gemm(Abf[1], wkT, acc, l, w); // no barrier needed vs Q-writeback
        __syncthreads();                 // all waves done reading Abf[1]
        writeback(Abf[1], acc, bk, l, w);
    }
    __syncthreads();

    // ---- phase 3: scores, softmax diagonal, activity mean ----
    if (t < 128) {
        const int e = t >> 5, h = (t >> 3) & 3, q = t & 7;
        float qv[64];
        #pragma unroll
        for (int c = 0; c < 8; ++c) {
            short8 v = *(const short8*)&Abf[0][e * 8 + q][h * 64 + c * 8];
            #pragma unroll
            for (int j = 0; j < 8; ++j) qv[c * 8 + j] = bf2f((unsigned short)v[j]);
        }
        float sc[8];
        #pragma unroll
        for (int k = 0; k < 8; ++k) {
            float d = 0.f;
            #pragma unroll
            for (int c = 0; c < 8; ++c) {
                short8 kv = *(const short8*)&Abf[1][e * 8 + k][h * 64 + c * 8];
                #pragma unroll
                for (int j = 0; j < 8; ++j) d = fmaf(qv[c * 8 + j], bf2f((unsigned short)kv[j]), d);
            }
            sc[k] = d * SCALE_V;
        }
        float mx = sc[0];
        #pragma unroll
        for (int k = 1; k < 8; ++k) mx = fmaxf(mx, sc[k]);
        float sum = 0.f, pd = 0.f;
        #pragma unroll
        for (int k = 0; k < 8; ++k) {
            float p = __expf(sc[k] - mx);
            sum += p;
            if (k == q) pd = p;
        }
        float dg = pd / sum;                 // softmax diagonal element
        #pragma unroll
        for (int off = 1; off < 32; off <<= 1) dg += __shfl_xor(dg, off);
        if ((t & 31) == 0) actLds[e] = dg * (1.0f / 32.0f);   // mean over NH*K
    }
    __syncthreads();

    // ---- phase 4: final 3 -> 16 -> 1 MLP ----
    if (t < TE) {
        const int ge = blockIdx.x * TE + t;
        const float s0 = attr_ws[ge];
        const float s1 = actLds[t];
        const float s2 = edge_ws[ge];
        float acc = bo2[0];
        #pragma unroll
        for (int j = 0; j < 16; ++j) {
            float z = s0 * Wo1[j] + s1 * Wo1[16 + j] + s2 * Wo1[32 + j] + bo1[j];
            acc += gelu_exact(z) * Wo2[j];
        }
        out[ge] = sigmoidf(acc);
    }
}

// ---------------------------------------------------------------------------
extern "C" void kernel_launch(void* const* d_in, const int* in_sizes, int n_in,
                              void* d_out, int out_size, void* d_ws, size_t ws_size,
                              hipStream_t stream) {
    const float* x_i  = (const float*)d_in[0];
    const float* x_j  = (const float*)d_in[1];
    const float* h_i  = (const float*)d_in[2];
    const float* h_j  = (const float*)d_in[3];
    const float* emb  = (const float*)d_in[4];
    const float* Wq   = (const float*)d_in[5];
    const float* bq   = (const float*)d_in[6];
    const float* Wk   = (const float*)d_in[7];
    const float* bk   = (const float*)d_in[8];
    const float* We1  = (const float*)d_in[9];
    const float* be1  = (const float*)d_in[10];
    const float* We2  = (const float*)d_in[11];
    const float* be2  = (const float*)d_in[12];
    const float* Wo1  = (const float*)d_in[13];
    const float* bo1  = (const float*)d_in[14];
    const float* Wo2  = (const float*)d_in[15];
    const float* bo2  = (const float*)d_in[16];
    float* out = (float*)d_out;

    // workspace layout
    unsigned short* wqT = (unsigned short*)d_ws;              // 131072 B
    unsigned short* wkT = wqT + 65536;                        // 131072 B
    unsigned short* wb1 = wkT + 65536;                        //  65536 B
    float* attr_ws = (float*)((char*)d_ws + 327680);          // 200000 B
    float* edge_ws = attr_ws + E_TOT;                         // 200000 B

    prep_weights<<<640, 256, 0, stream>>>(Wq, Wk, We1, wqT, wkT, wb1);
    score_attr_edge<<<E_TOT / 4, 256, 0, stream>>>(x_i, x_j, emb, wb1, be1, We2, be2,
                                                   attr_ws, edge_ws);
    fused_attn<<<E_TOT / TE, 256, 0, stream>>>(h_i, h_j, wqT, wkT, bq, bk,
                                               Wo1, bo1, Wo2, bo2,
                                               attr_ws, edge_ws, out);
}